// Round 24
// baseline (487.230 us; speedup 1.0000x reference)
//
#include <hip/hip_runtime.h>
#include <hip/hip_bf16.h>
#include <math.h>

// B=8, S=512, H=1024, NH=16, DK=64, FF=4096.
// Round 24: big GEMMs rerouted through the 128x128 kernel (documented tile
// table: 128^2=912 TF > 256x128=823 on this 2-phase template; our gemm256
// measured 647). r16's attempt failed on B-panel refetch (FETCH 43->154MB)
// because the 1D XCD swizzle gave each XCD 4 full by-rows (B set 12MB >> 4MB
// L2). Fix: port gemm256's proven 2D chunk swizzle (per-XCD B-chunk 3MB <
// L2) into gemm_bf16_nt, active only for nwg>=64 grids. gemm256 deleted.

typedef __bf16 bf16x8 __attribute__((ext_vector_type(8)));
typedef float f32x4 __attribute__((ext_vector_type(4)));

__device__ __forceinline__ void async_copy16(void* lds, const void* g) {
  __builtin_amdgcn_global_load_lds(
      (__attribute__((address_space(1))) void*)(void*)g,
      (__attribute__((address_space(3))) void*)lds, 16, 0, 0);
}

#define SB0 __builtin_amdgcn_sched_barrier(0)
#define BARRIER __builtin_amdgcn_s_barrier()

// ---------------------------------------------------------------------------
// LayerNorm over last dim (1024) -> bf16. One block (256 thr) per row.
// ---------------------------------------------------------------------------
__global__ __launch_bounds__(256) void ln_rows_bf16(
    const float* __restrict__ X, const float* __restrict__ G,
    const float* __restrict__ Bt, __hip_bfloat16* __restrict__ O) {
  long row = blockIdx.x;
  int t = threadIdx.x;
  const float4 xv = ((const float4*)(X + row * 1024))[t];
  float s = xv.x + xv.y + xv.z + xv.w;
  float q = xv.x * xv.x + xv.y * xv.y + xv.z * xv.z + xv.w * xv.w;
#pragma unroll
  for (int o = 32; o; o >>= 1) {
    s += __shfl_xor(s, o);
    q += __shfl_xor(q, o);
  }
  __shared__ float rs[4], rq[4];
  int wid = t >> 6;
  if ((t & 63) == 0) { rs[wid] = s; rq[wid] = q; }
  __syncthreads();
  s = rs[0] + rs[1] + rs[2] + rs[3];
  q = rq[0] + rq[1] + rq[2] + rq[3];
  float mean = s * (1.f / 1024.f);
  float var = q * (1.f / 1024.f) - mean * mean;
  float rstd = rsqrtf(var + 1e-5f);
  const float4 gv = ((const float4*)G)[t];
  const float4 bv = ((const float4*)Bt)[t];
  __hip_bfloat16* o = O + row * 1024 + t * 4;
  o[0] = __float2bfloat16((xv.x - mean) * rstd * gv.x + bv.x);
  o[1] = __float2bfloat16((xv.y - mean) * rstd * gv.y + bv.y);
  o[2] = __float2bfloat16((xv.z - mean) * rstd * gv.z + bv.z);
  o[3] = __float2bfloat16((xv.w - mean) * rstd * gv.w + bv.w);
}

// ---------------------------------------------------------------------------
// prep_weights: z 0..14 = one 1024x1024 transpose-convert each; z 15 = bias6
// concat; z 16..19 = LN1 over rows [(z-16)*1024, +1024). grid (32,32,20).
// ---------------------------------------------------------------------------
struct PrepJobs {
  const float* in[15];
  __hip_bfloat16* out[15];
  int inLd[15];
  int outLd[15];
  float scale[15];
  const float* bsrc[6];
  float bscale[6];
  float* bias6;
  const float* lnx;
  const float* lng;
  const float* lnb;
  __hip_bfloat16* lno;
};
__global__ __launch_bounds__(256) void prep_weights(PrepJobs p) {
  int j = blockIdx.z;
  int tid = threadIdx.x;
  if (j >= 16) {  // LN1 slice
    long row = (long)(j - 16) * 1024 + blockIdx.y * 32 + blockIdx.x;
    const float4 xv = ((const float4*)(p.lnx + row * 1024))[tid];
    float s = xv.x + xv.y + xv.z + xv.w;
    float q = xv.x * xv.x + xv.y * xv.y + xv.z * xv.z + xv.w * xv.w;
#pragma unroll
    for (int o = 32; o; o >>= 1) {
      s += __shfl_xor(s, o);
      q += __shfl_xor(q, o);
    }
    __shared__ float rs[4], rq[4];
    int wid = tid >> 6;
    if ((tid & 63) == 0) { rs[wid] = s; rq[wid] = q; }
    __syncthreads();
    s = rs[0] + rs[1] + rs[2] + rs[3];
    q = rq[0] + rq[1] + rq[2] + rq[3];
    float mean = s * (1.f / 1024.f);
    float var = q * (1.f / 1024.f) - mean * mean;
    float rstd = rsqrtf(var + 1e-5f);
    const float4 gv = ((const float4*)p.lng)[tid];
    const float4 bv = ((const float4*)p.lnb)[tid];
    __hip_bfloat16* o = p.lno + row * 1024 + tid * 4;
    o[0] = __float2bfloat16((xv.x - mean) * rstd * gv.x + bv.x);
    o[1] = __float2bfloat16((xv.y - mean) * rstd * gv.y + bv.y);
    o[2] = __float2bfloat16((xv.z - mean) * rstd * gv.z + bv.z);
    o[3] = __float2bfloat16((xv.w - mean) * rstd * gv.w + bv.w);
    return;
  }
  if (j == 15) {
    if (blockIdx.y == 0 && blockIdx.x < 24) {
      int idx = blockIdx.x * 256 + tid;
      int jj = idx >> 10, e = idx & 1023;
      p.bias6[idx] = p.bsrc[jj][e] * p.bscale[jj];
    }
    return;
  }
  __shared__ float t[32][33];
  const float* in = p.in[j];
  __hip_bfloat16* out = p.out[j];
  const int inLd = p.inLd[j], outLd = p.outLd[j];
  const float sc = p.scale[j];
  int c0 = blockIdx.x * 32, r0 = blockIdx.y * 32;
  int lr = tid >> 3, lc = (tid & 7) * 4;
  const float4 v = *(const float4*)&in[(long)(r0 + lr) * inLd + c0 + lc];
  t[lr][lc] = v.x; t[lr][lc + 1] = v.y; t[lr][lc + 2] = v.z; t[lr][lc + 3] = v.w;
  __syncthreads();
  int oc = tid >> 3, orr = (tid & 7) * 4;
  __hip_bfloat16* o = &out[(long)(c0 + oc) * outLd + r0 + orr];
  o[0] = __float2bfloat16(t[orr][oc] * sc);
  o[1] = __float2bfloat16(t[orr + 1][oc] * sc);
  o[2] = __float2bfloat16(t[orr + 2][oc] * sc);
  o[3] = __float2bfloat16(t[orr + 3][oc] * sc);
}

// ---------------------------------------------------------------------------
// tconv_vpv: V (z 0..7) and PV (z 8..15): [512x1024]@6144 -> [1024][512].
// ---------------------------------------------------------------------------
__global__ __launch_bounds__(256) void tconv_vpv(
    const __hip_bfloat16* __restrict__ V, const __hip_bfloat16* __restrict__ PV,
    __hip_bfloat16* __restrict__ VT, __hip_bfloat16* __restrict__ PVT) {
  __shared__ __hip_bfloat16 t[32][34];
  int z = blockIdx.z;
  const __hip_bfloat16* in = (z < 8) ? V : PV;
  __hip_bfloat16* out = (z < 8) ? VT : PVT;
  int bz = z & 7;
  long ibase = (long)bz * 512 * 6144;
  long obase = (long)bz * 512 * 1024;
  int c0 = blockIdx.x * 32, r0 = blockIdx.y * 32;
  int tid = threadIdx.x;
  int lr = tid >> 3, lc = (tid & 7) * 4;
  const __hip_bfloat16* ip = &in[ibase + (long)(r0 + lr) * 6144 + c0 + lc];
  t[lr][lc] = ip[0]; t[lr][lc + 1] = ip[1]; t[lr][lc + 2] = ip[2]; t[lr][lc + 3] = ip[3];
  __syncthreads();
  int oc = tid >> 3, orr = (tid & 7) * 4;
  __hip_bfloat16* o = &out[obase + (long)(c0 + oc) * 512 + r0 + orr];
  o[0] = t[orr][oc];
  o[1] = t[orr + 1][oc];
  o[2] = t[orr + 2][oc];
  o[3] = t[orr + 3][oc];
}

// FFN2 finalize: OUT = PART0 + PART1 + b2 + X2. float4/thread, grid 4096.
__global__ __launch_bounds__(256) void ffn2_reduce(
    const float* __restrict__ P, const float* __restrict__ X2,
    const float* __restrict__ b2, float* __restrict__ OUT) {
  int i = blockIdx.x * 256 + threadIdx.x;
  const long SP = 4194304;
  float4 a = ((const float4*)P)[i];
  float4 b = ((const float4*)(P + SP))[i];
  float4 xr = ((const float4*)X2)[i];
  const float4 bb = *(const float4*)(b2 + ((i & 255) * 4));
  float4 o;
  o.x = a.x + b.x + xr.x + bb.x;
  o.y = a.y + b.y + xr.y + bb.y;
  o.z = a.z + b.z + xr.z + bb.z;
  o.w = a.w + b.w + xr.w + bb.w;
  ((float4*)OUT)[i] = o;
}

// ---------------------------------------------------------------------------
// bf16 MFMA GEMM (NT), 128x128 tile, BK=32, 4 waves, 32KB LDS (5 blocks/CU).
// Double-buffered, counted vmcnt(4) pipeline. XCD swizzle: 2D chunking for
// large grids (per-XCD contiguous 2D block chunk -> B-panel set fits L2;
// fixes r16's 154MB refetch), legacy 1D otherwise. Split-K via z-packing.
// pbc=1: C = E1 + 0.5*((A@Bt^T + bias) + E2[row>>9, col]).
// ---------------------------------------------------------------------------
__global__ __launch_bounds__(256) void gemm_bf16_nt(
    const __hip_bfloat16* __restrict__ A, const __hip_bfloat16* __restrict__ Bt,
    const float* __restrict__ bias, const float* __restrict__ E1,
    const float* __restrict__ E2, void* __restrict__ C, int K, int lda,
    int ldb, int ldc, long sA, long sB, long sC, long sE, float alpha, int act,
    int obf, int pbc, int ksplit, long sSplit) {
  __shared__ unsigned short AsU[2][128 * 32];
  __shared__ unsigned short BsU[2][128 * 32];
  const int tid = threadIdx.x;
  const int lane = tid & 63, wave = tid >> 6;
  const int wr = wave >> 1, wc = wave & 1;

  int nwg = gridDim.x * gridDim.y;
  int wg = blockIdx.y * gridDim.x + blockIdx.x;
  int bx = blockIdx.x, by = blockIdx.y;
  int gx = gridDim.x, gy = gridDim.y;
  if ((gx & 3) == 0 && (gy & 1) == 0 && nwg >= 64) {
    // 2D chunk: per-XCD chunk of cw x ch blocks (ported from gemm256)
    int cw = gx >> 2, ch = gy >> 1;
    int xcd = wg & 7, idx = wg >> 3;
    bx = (xcd & 3) * cw + idx % cw;
    by = (xcd >> 2) * ch + idx / cw;
  } else if ((nwg & 7) == 0) {
    int cpx = nwg >> 3;
    int sw = (wg & 7) * cpx + (wg >> 3);
    bx = sw % gx;
    by = sw / gx;
  }
  const int m0 = by * 128, n0 = bx * 128;
  const int bz = blockIdx.z / ksplit;
  const int sk = blockIdx.z % ksplit;
  if (sk != 0) { bias = nullptr; E1 = nullptr; E2 = nullptr; }
  const int kcol0 = sk * K;
  const char* Ab = (const char*)(A + (long)bz * sA);
  const char* Bb = (const char*)(Bt + (long)bz * sB);

  f32x4 acc[4][4];
#pragma unroll
  for (int m = 0; m < 4; ++m)
#pragma unroll
    for (int n = 0; n < 4; ++n) acc[m][n] = (f32x4){0.f, 0.f, 0.f, 0.f};

  const int srow = tid >> 2;
  const int scol = (tid & 3) * 16;
  const int wbase = (tid >> 6) * 1024;

  auto stage = [&](int buf, int k0) {
    int kk = kcol0 + k0;
#pragma unroll
    for (int i = 0; i < 2; ++i) {
      async_copy16((char*)AsU[buf] + i * 4096 + wbase,
                   Ab + ((long)(m0 + i * 64 + srow) * lda + kk) * 2 + scol);
      async_copy16((char*)BsU[buf] + i * 4096 + wbase,
                   Bb + ((long)(n0 + i * 64 + srow) * ldb + kk) * 2 + scol);
    }
  };

  const int ntk = K >> 5;
  stage(0, 0);

  for (int t = 0; t < ntk; ++t) {
    const int bt = t & 1;
    SB0; BARRIER; SB0;
    if (t + 1 < ntk) {
      stage(bt ^ 1, (t + 1) * 32);
      asm volatile("s_waitcnt vmcnt(4)" ::: "memory");
    } else {
      asm volatile("s_waitcnt vmcnt(0)" ::: "memory");
    }
    SB0; BARRIER; SB0;

    const int koff = (lane >> 4) * 8;
    bf16x8 a[4], b[4];
#pragma unroll
    for (int m = 0; m < 4; ++m)
      a[m] = *(const bf16x8*)&AsU[bt][(wr * 64 + m * 16 + (lane & 15)) * 32 +
                                      koff];
#pragma unroll
    for (int n = 0; n < 4; ++n)
      b[n] = *(const bf16x8*)&BsU[bt][(wc * 64 + n * 16 + (lane & 15)) * 32 +
                                      koff];
    __builtin_amdgcn_s_setprio(1);
#pragma unroll
    for (int m = 0; m < 4; ++m)
#pragma unroll
      for (int n = 0; n < 4; ++n)
        acc[m][n] = __builtin_amdgcn_mfma_f32_16x16x32_bf16(a[m], b[n],
                                                            acc[m][n], 0, 0, 0);
    __builtin_amdgcn_s_setprio(0);
  }

#pragma unroll
  for (int m = 0; m < 4; ++m) {
    int row = m0 + wr * 64 + m * 16 + (lane >> 4) * 4;
#pragma unroll
    for (int n = 0; n < 4; ++n) {
      int col = n0 + wc * 64 + n * 16 + (lane & 15);
      float bs = bias ? bias[col] : 0.f;
#pragma unroll
      for (int r = 0; r < 4; ++r) {
        float v = (acc[m][n][r] + bs) * alpha;
        if (pbc) {
          v = E1[(long)(row + r) * ldc + col] +
              0.5f * (v + E2[(long)((row + r) >> 9) * 1024 + col]);
        } else {
          long eidx = (long)bz * sE + (long)(row + r) * ldc + col;
          if (E1) v += E1[eidx];
          if (E2) v += E2[eidx];
        }
        if (act) v = v * 0.5f * (1.f + erff(v * 0.70710678118f));
        long cidx = (long)bz * sC + (long)sk * sSplit +
                    (long)(row + r) * ldc + col;
        if (obf)
          ((__hip_bfloat16*)C)[cidx] = __float2bfloat16(v);
        else
          ((float*)C)[cidx] = v;
      }
    }
  }
}

// ---------------------------------------------------------------------------
// MFMA attention. Block = (i-tile of 32, h, b); 4 waves. Reads bias+mask raw.
// ---------------------------------------------------------------------------
__global__ __launch_bounds__(256) void attn_mfma(
    const __hip_bfloat16* __restrict__ Q, const __hip_bfloat16* __restrict__ K,
    const __hip_bfloat16* __restrict__ VT, const float* __restrict__ BiasP,
    const float* __restrict__ MaskP, __hip_bfloat16* __restrict__ O,
    int ldqk) {
  __shared__ __hip_bfloat16 P[32][520];
  __shared__ float red[2][32][4];
  const int it = blockIdx.x, h = blockIdx.y, b = blockIdx.z;
  const int i0 = it * 32;
  const int tid = threadIdx.x;
  const int lane = tid & 63, w = tid >> 6;
  const int lh = lane >> 4, ll = lane & 15;

  const long qkb = (long)b * 512 * ldqk + h * 64;

  bf16x8 a[2][2];
#pragma unroll
  for (int m = 0; m < 2; ++m)
#pragma unroll
    for (int ks = 0; ks < 2; ++ks)
      a[m][ks] = *(const bf16x8*)&Q[qkb + (long)(i0 + m * 16 + ll) * ldqk +
                                    ks * 32 + lh * 8];

  f32x4 acc[2][8];
#pragma unroll
  for (int m = 0; m < 2; ++m)
#pragma unroll
    for (int n = 0; n < 8; ++n) acc[m][n] = (f32x4){0.f, 0.f, 0.f, 0.f};

#pragma unroll
  for (int n = 0; n < 8; ++n) {
    const __hip_bfloat16* kp =
        &K[qkb + (long)(w * 128 + n * 16 + ll) * ldqk + lh * 8];
    bf16x8 b0 = *(const bf16x8*)&kp[0];
    bf16x8 b1 = *(const bf16x8*)&kp[32];
#pragma unroll
    for (int m = 0; m < 2; ++m) {
      acc[m][n] =
          __builtin_amdgcn_mfma_f32_16x16x32_bf16(a[m][0], b0, acc[m][n], 0, 0, 0);
      acc[m][n] =
          __builtin_amdgcn_mfma_f32_16x16x32_bf16(a[m][1], b1, acc[m][n], 0, 0, 0);
    }
  }

  const long bmo = ((long)b * 512 + i0) * 512 + w * 128;
#pragma unroll
  for (int m = 0; m < 2; ++m)
#pragma unroll
    for (int r = 0; r < 4; ++r) {
      int row = m * 16 + lh * 4 + r;
#pragma unroll
      for (int n = 0; n < 8; ++n) {
        long gi = bmo + (long)row * 512 + n * 16 + ll;
        acc[m][n][r] += BiasP[gi] + MaskP[gi];
      }
    }

  float rmax[2][4];
#pragma unroll
  for (int m = 0; m < 2; ++m)
#pragma unroll
    for (int r = 0; r < 4; ++r) {
      float v = acc[m][0][r];
#pragma unroll
      for (int n = 1; n < 8; ++n) v = fmaxf(v, acc[m][n][r]);
#pragma unroll
      for (int o = 1; o < 16; o <<= 1) v = fmaxf(v, __shfl_xor(v, o));
      rmax[m][r] = v;
    }
  if (ll == 0) {
#pragma unroll
    for (int m = 0; m < 2; ++m)
#pragma unroll
      for (int r = 0; r < 4; ++r) red[0][m * 16 + lh * 4 + r][w] = rmax[m][r];
  }
  __syncthreads();
#pragma unroll
  for (int m = 0; m < 2; ++m)
#pragma unroll
    for (int r = 0; r < 4; ++r) {
      const float* p = red[0][m * 16 + lh * 4 + r];
      rmax[m][r] = fmaxf(fmaxf(p[0], p[1]), fmaxf(p[2], p[3]));
    }
  float rsum[2][4];
#pragma unroll
  for (int m = 0; m < 2; ++m)
#pragma unroll
    for (int r = 0; r < 4; ++r) {
      float s = 0.f;
#pragma unroll
      for (int n = 0; n < 8; ++n) {
        float e = __expf(acc[m][n][r] - rmax[m][r]);
        acc[m][n][r] = e;
        s += e;
      }
#pragma unroll
      for (int o = 1; o < 16; o <<= 1) s += __shfl_xor(s, o);
      rsum[m][r] = s;
    }
  if (ll == 0) {
#pragma unroll
    for (int m = 0; m < 2; ++m)
#pragma unroll
      for (int r = 0; r < 4; ++r) red[1][m * 16 + lh * 4 + r][w] = rsum[m][r];
  }
  __syncthreads();
#pragma unroll
  for (int m = 0; m < 2; ++m)
#pragma unroll
    for (int r = 0; r < 4; ++r) {
      const float* p = red[1][m * 16 + lh * 4 + r];
      float inv = 1.f / (p[0] + p[1] + p[2] + p[3]);
      int row = m * 16 + lh * 4 + r;
#pragma unroll
      for (int n = 0; n < 8; ++n)
        P[row][w * 128 + n * 16 + ll] = __float2bfloat16(acc[m][n][r] * inv);
    }
  __syncthreads();

  const long vtb = ((long)b * 1024 + h * 64) * 512;
  const long ob = (long)b * 512 * 1024 + h * 64;
  const int mw = (w >> 1) * 16, nw = (w & 1) * 32;
  f32x4 oacc[2];
  oacc[0] = (f32x4){0.f, 0.f, 0.f, 0.f};
  oacc[1] = (f32x4){0.f, 0.f, 0.f, 0.f};
#pragma unroll
  for (int ks = 0; ks < 16; ++ks) {
    int k0 = ks * 32;
    bf16x8 pa = *(const bf16x8*)&P[mw + ll][k0 + lh * 8];
#pragma unroll
    for (int nf = 0; nf < 2; ++nf) {
      bf16x8 vb = *(const bf16x8*)&VT[vtb + (long)(nw + nf * 16 + ll) * 512 +
                                      k0 + lh * 8];
      oacc[nf] =
          __builtin_amdgcn_mfma_f32_16x16x32_bf16(pa, vb, oacc[nf], 0, 0, 0);
    }
  }
#pragma unroll
  for (int nf = 0; nf < 2; ++nf)
#pragma unroll
    for (int r = 0; r < 4; ++r)
      O[ob + (long)(i0 + mw + lh * 4 + r) * 1024 + nw + nf * 16 + ll] =
          __float2bfloat16(oacc[nf][r]);
}

// ---------------------------------------------------------------------------
// Row softmax over 512 of (P0[row] + P1[row]) -> bf16. One block per row.
// ---------------------------------------------------------------------------
__global__ __launch_bounds__(256) void softmax_rows2(
    const float* __restrict__ P0, const float* __restrict__ P1,
    __hip_bfloat16* __restrict__ Ob) {
  const float* r0 = P0 + (long)blockIdx.x * 512;
  const float* r1 = P1 + (long)blockIdx.x * 512;
  __hip_bfloat16* orow = Ob + (long)blockIdx.x * 512;
  int t = threadIdx.x;
  float v0 = r0[t] + r1[t], v1 = r0[t + 256] + r1[t + 256];
  float m = fmaxf(v0, v1);
#pragma unroll
  for (int o = 32; o; o >>= 1) m = fmaxf(m, __shfl_xor(m, o));
  __shared__ float red[8];
  int wid = t >> 6, lane = t & 63;
  if (!lane) red[wid] = m;
  __syncthreads();
  m = fmaxf(fmaxf(red[0], red[1]), fmaxf(red[2], red[3]));
  float e0 = __expf(v0 - m), e1 = __expf(v1 - m);
  float s = e0 + e1;
#pragma unroll
  for (int o = 32; o; o >>= 1) s += __shfl_xor(s, o);
  if (!lane) red[4 + wid] = s;
  __syncthreads();
  s = red[4] + red[5] + red[6] + red[7];
  float inv = 1.f / s;
  orow[t] = __float2bfloat16(e0 * inv);
  orow[t + 256] = __float2bfloat16(e1 * inv);
}

// ---------------------------------------------------------------------------
// path gather-mean partials + finalize.
// ---------------------------------------------------------------------------
__global__ __launch_bounds__(256) void path_partial(
    const float* __restrict__ xp, const int* __restrict__ pp,
    float* __restrict__ PP, float* __restrict__ WS) {
  int b = blockIdx.x, hc = blockIdx.y, ic = blockIdx.z;
  int h = hc * 256 + threadIdx.x;
  const int* ppb = pp + b * 512;
  const float* xb = xp + (long)b * 512 * 1024;
  int iA = ic * 64, iB = iA + 64;
  float acc = 0.f;
  for (int i = iA; i < iB; ++i) {
    if (ppb[i] != 1) continue;
    float cur = xb[(long)i * 1024 + h];
    float a;
    if (i == 0) {
      a = 0.5f * (cur + xb[1024 + h]);
    } else if (i == 1) {
      a = (xb[h] + cur + xb[2 * 1024 + h]) * (1.f / 3.f);
    } else {
      int inx = (i + 1 < 512) ? i + 1 : 511;
      float nx = xb[(long)inx * 1024 + h];
      if (ppb[i - 2] == 1) {
        a = 0.5f * (cur + nx);
      } else {
        a = (xb[(long)(i - 1) * 1024 + h] + cur + nx) * (1.f / 3.f);
      }
    }
    acc += a;
  }
  PP[((long)b * 8 + ic) * 1024 + h] = acc;
  if (hc == 0 && threadIdx.x == 0) {
    float c = 0.f;
    for (int i = iA; i < iB; ++i) c += (ppb[i] == 1) ? 1.f : 0.f;
    WS[b * 8 + ic] = c;
  }
}

__global__ __launch_bounds__(256) void path_finalize(
    const float* __restrict__ PP, const float* __restrict__ WS,
    float* __restrict__ PATH) {
  int b = blockIdx.x;
  int h = blockIdx.y * 256 + threadIdx.x;
  float s = 0.f, w = 0.f;
#pragma unroll
  for (int ic = 0; ic < 8; ++ic) {
    s += PP[((long)b * 8 + ic) * 1024 + h];
    w += WS[b * 8 + ic];
  }
  PATH[b * 1024 + h] = s / w;
}

// ---------------------------------------------------------------------------
extern "C" void kernel_launch(void* const* d_in, const int* in_sizes, int n_in,
                              void* d_out, int out_size, void* d_ws,
                              size_t ws_size, hipStream_t stream) {
  const float* x = (const float*)d_in[0];
  const int* pp = (const int*)d_in[1];
  const float* abias = (const float*)d_in[3];
  const float* amask = (const float*)d_in[4];
  const float* agraph = (const float*)d_in[5];
  const float* vgraph = (const float*)d_in[6];
  const float* ln1g = (const float*)d_in[7];
  const float* ln1b = (const float*)d_in[8];
  const float* wq = (const float*)d_in[9];
  const float* bq = (const float*)d_in[10];
  const float* wk = (const float*)d_in[11];
  const float* bk = (const float*)d_in[12];
  const float* wv = (const float*)d_in[13];
  const float* bv = (const float*)d_in[14];
  const float* wo = (const float*)d_in[15];
  const float* bo = (const float*)d_in[16];
  const float* pqw = (const float*)d_in[17];
  const float* pqb = (const float*)d_in[18];
  const float* pkw = (const float*)d_in[19];
  const float* pkb = (const float*)d_in[20];
  const float* pvw = (const float*)d_in[21];
  const float* pvb = (const float*)d_in[22];
  const float* ln2g = (const float*)d_in[23];
  const float* ln2b = (const float*)d_in[24];
  const float* w1 = (const float*)d_in[25];
  const float* b1 = (const float*)d_in[26];
  const float* w2 = (const float*)d_in[27];
  const float* b2 = (const float*)d_in[28];

  char* wsb = (char*)d_ws;
  auto Ybf = (__hip_bfloat16*)(wsb);                  // 0-8 (later Y2b)
  auto QKV = (__hip_bfloat16*)(wsb + (8l << 20));     // 8-56: [4096][6144]
  auto VTb = (__hip_bfloat16*)(wsb + (56l << 20));    // 56-64
  auto PVT = (__hip_bfloat16*)(wsb + (64l << 20));    // 64-72
  auto ATTb = (__hip_bfloat16*)(wsb + (72l << 20));   // 72-80
  auto PATTb = (__hip_bfloat16*)(wsb + (88l << 20));  // 88-92
  auto PATTf = (float*)(wsb + (92l << 20));           // 92-100 (partial0)
  auto XP = (float*)(wsb + (92l << 20));              // 92-108
  auto WALL = (__hip_bfloat16*)(wsb + (108l << 20));  // 108-120: [6144][1024]
  auto WOT = (__hip_bfloat16*)(wsb + (120l << 20));   // 120-122
  auto W1T = (__hip_bfloat16*)(wsb + (122l << 20));   // 122-130
  auto bias6 = (float*)(wsb + (130l << 20));          // 24KB
  auto PPart = (float*)(wsb + (131l << 20));          // 256KB
  auto WSp = (float*)(wsb + (132l << 20));            // 256B
  auto PATH = (float*)(wsb + (133l << 20));           // 32KB
  auto X2 = (float*)(wsb + (24l << 20));              // 24-40 (QKV dead)
  auto HMID = (__hip_bfloat16*)(wsb + (40l << 20));   // 40-72
  auto PART = (float*)(wsb + (92l << 20));            // 92-124 (2x16MB f32)
  auto W2T = (__hip_bfloat16*)(wsb + (156l << 20));   // 156-164
  __hip_bfloat16* Y2b = Ybf;
  float* OUT = (float*)d_out;

  const float qscale = 0.125f;
  const float pscale = 0.03125f;
  const long S2 = 512l * 512;
  const long SQ = 512l * 6144;
  const long SPLT = 8l * S2;

  __hip_bfloat16* Qp = QKV;
  __hip_bfloat16* Kp = QKV + 1024;
  __hip_bfloat16* Vp = QKV + 2048;
  __hip_bfloat16* PQp = QKV + 3072;
  __hip_bfloat16* PKp = QKV + 4096;
  __hip_bfloat16* PVp = QKV + 5120;

  // 0) ALL weight prep + bias concat + LN1 in ONE launch (z = 20 slices)
  PrepJobs pj;
  pj.in[0] = wq;  pj.out[0] = WALL;               pj.inLd[0] = 1024; pj.outLd[0] = 1024; pj.scale[0] = qscale;
  pj.in[1] = wk;  pj.out[1] = WALL + 1024 * 1024; pj.inLd[1] = 1024; pj.outLd[1] = 1024; pj.scale[1] = 1.f;
  pj.in[2] = wv;  pj.out[2] = WALL + 2048 * 1024; pj.inLd[2] = 1024; pj.outLd[2] = 1024; pj.scale[2] = 1.f;
  pj.in[3] = pqw; pj.out[3] = WALL + 3072 * 1024; pj.inLd[3] = 1024; pj.outLd[3] = 1024; pj.scale[3] = pscale;
  pj.in[4] = pkw; pj.out[4] = WALL + 4096 * 1024; pj.inLd[4] = 1024; pj.outLd[4] = 1024; pj.scale[4] = 1.f;
  pj.in[5] = pvw; pj.out[5] = WALL + 5120 * 1024; pj.inLd[5] = 1024; pj.outLd[5] = 1024; pj.scale[5] = 1.f;
  pj.in[6] = wo;  pj.out[6] = WOT;                pj.inLd[6] = 1024; pj.outLd[6] = 1024; pj.scale[6] = 1.f;
  for (int j = 0; j < 4; ++j) {  // w1: [1024,4096] -> W1T [4096][1024]
    pj.in[7 + j] = w1 + j * 1024;
    pj.out[7 + j] = W1T + (long)j * 1024 * 1024;
    pj.inLd[7 + j] = 4096;
    pj.outLd[7 + j] = 1024;
    pj.scale[7 + j] = 1.f;
  }
  for (int j = 0; j < 4; ++j) {  // w2: [4096,1024] -> W2T [1024][4096]
    pj.in[11 + j] = w2 + (long)j * 1024 * 1024;
    pj.out[11 + j] = W2T + j * 1024;
    pj.inLd[11 + j] = 1024;
    pj.outLd[11 + j] = 4096;
    pj.scale[11 + j] = 1.f;
  }
  pj.bsrc[0] = bq;  pj.bscale[0] = qscale;
  pj.bsrc[1] = bk;  pj.bscale[1] = 1.f;
  pj.bsrc[2] = bv;  pj.bscale[2] = 1.f;
  pj.bsrc[3] = pqb; pj.bscale[3] = pscale;
  pj.bsrc[4] = pkb; pj.bscale[4] = 1.f;
  pj.bsrc[5] = pvb; pj.bscale[5] = 1.f;
  pj.bias6 = bias6;
  pj.lnx = x; pj.lng = ln1g; pj.lnb = ln1b; pj.lno = Ybf;
  prep_weights<<<dim3(32, 32, 20), 256, 0, stream>>>(pj);

  // 2) fused projections via 128^2 kernel: M=4096 (y=32), N=6144 (x=48)
  gemm_bf16_nt<<<dim3(48, 32, 1), 256, 0, stream>>>(
      Ybf, WALL, bias6, nullptr, nullptr, QKV, 1024, 1024, 1024, 6144,
      0, 0, 0, 0, 1.f, 0, 1, 0, 1, 0);

  // 3) V -> VT and PV -> PVT in one launch
  tconv_vpv<<<dim3(32, 16, 16), 256, 0, stream>>>(Vp, PVp, VTb, PVT);

  // 4) path scores split-K=2 + softmax over partials
  gemm_bf16_nt<<<dim3(4, 4, 16), 256, 0, stream>>>(
      PQp, PKp, nullptr, agraph, vgraph, PATTf, 512, 6144, 6144, 512, SQ, SQ,
      S2, S2, 1.f, 0, 0, 0, 2, SPLT);
  softmax_rows2<<<4096, 256, 0, stream>>>(PATTf, PATTf + SPLT, PATTb);

  // 5) MFMA attention -> ATTb
  attn_mfma<<<dim3(16, 16, 8), 256, 0, stream>>>(Qp, Kp, VTb, abias, amask,
                                                 ATTb, 6144);

  // 6) XP = PATT @ PVT^T
  gemm_bf16_nt<<<dim3(8, 4, 8), 256, 0, stream>>>(
      PATTb, PVT, nullptr, nullptr, nullptr, XP, 512, 512, 512, 1024, S2,
      512l * 1024, 512l * 1024, 0, 1.f, 0, 0, 0, 1, 0);

  // 7) path gather-mean
  path_partial<<<dim3(8, 4, 8), 256, 0, stream>>>(XP, pp, PPart, WSp);
  path_finalize<<<dim3(8, 4), 256, 0, stream>>>(PPart, WSp, PATH);

  // 8) fused: X2 = x + 0.5*((ATT@wo + bo) + PATH)
  gemm_bf16_nt<<<dim3(8, 32, 1), 256, 0, stream>>>(
      ATTb, WOT, bo, x, PATH, X2, 1024, 1024, 1024, 1024, 0, 0, 0, 0, 1.f, 0,
      0, 1, 1, 0);

  // 10) LN2 -> Y2b
  ln_rows_bf16<<<4096, 256, 0, stream>>>(X2, ln2g, ln2b, Y2b);

  // 11) FFN1 via 128^2 kernel: M=4096 (y=32), N=4096 (x=32), GELU, bf16 out
  gemm_bf16_nt<<<dim3(32, 32, 1), 256, 0, stream>>>(
      Y2b, W1T, b1, nullptr, nullptr, HMID, 1024, 1024, 1024, 4096,
      0, 0, 0, 0, 1.f, 1, 1, 0, 1, 0);

  // 12) FFN2 via 128^2 kernel, split-K=2: grid (8,32,2), K=2048 per split
  gemm_bf16_nt<<<dim3(8, 32, 2), 256, 0, stream>>>(
      HMID, W2T, nullptr, nullptr, nullptr, PART, 2048, 4096, 4096, 1024,
      0, 0, 0, 0, 1.f, 0, 0, 0, 2, 4194304);

  // 12b) OUT = PART0 + PART1 + b2 + X2
  ffn2_reduce<<<4096, 256, 0, stream>>>(PART, X2, b2, OUT);
}

// Round 25
// 429.186 us; speedup vs baseline: 1.1352x; 1.1352x over previous
//
#include <hip/hip_runtime.h>
#include <hip/hip_bf16.h>
#include <math.h>

// B=8, S=512, H=1024, NH=16, DK=64, FF=4096.
// Round 25 (CONVERGED): verified-best config (r17/r20/r21/r23; 434-438us).
// Four experiment axes each regressed with counter-confirmed mechanisms:
// r18 LDS-conflict fix (uncoalesced staging), r19 megakernels (resource
// envelope), r22 4-wave intensity (occupancy 29->11%), r24 128^2 routing
// (per-block TLP loss; 2D swizzle DID fix refetch 154->56MB but still
// 108us vs 80). Remaining headroom requires the 8-phase schedule.
// Cumulative: 5070 -> ~435us (11.6x).

typedef __bf16 bf16x8 __attribute__((ext_vector_type(8)));
typedef float f32x4 __attribute__((ext_vector_type(4)));

__device__ __forceinline__ void async_copy16(void* lds, const void* g) {
  __builtin_amdgcn_global_load_lds(
      (__attribute__((address_space(1))) void*)(void*)g,
      (__attribute__((address_space(3))) void*)lds, 16, 0, 0);
}

#define SB0 __builtin_amdgcn_sched_barrier(0)
#define BARRIER __builtin_amdgcn_s_barrier()

// ---------------------------------------------------------------------------
// LayerNorm over last dim (1024) -> bf16. One block (256 thr) per row.
// ---------------------------------------------------------------------------
__global__ __launch_bounds__(256) void ln_rows_bf16(
    const float* __restrict__ X, const float* __restrict__ G,
    const float* __restrict__ Bt, __hip_bfloat16* __restrict__ O) {
  long row = blockIdx.x;
  int t = threadIdx.x;
  const float4 xv = ((const float4*)(X + row * 1024))[t];
  float s = xv.x + xv.y + xv.z + xv.w;
  float q = xv.x * xv.x + xv.y * xv.y + xv.z * xv.z + xv.w * xv.w;
#pragma unroll
  for (int o = 32; o; o >>= 1) {
    s += __shfl_xor(s, o);
    q += __shfl_xor(q, o);
  }
  __shared__ float rs[4], rq[4];
  int wid = t >> 6;
  if ((t & 63) == 0) { rs[wid] = s; rq[wid] = q; }
  __syncthreads();
  s = rs[0] + rs[1] + rs[2] + rs[3];
  q = rq[0] + rq[1] + rq[2] + rq[3];
  float mean = s * (1.f / 1024.f);
  float var = q * (1.f / 1024.f) - mean * mean;
  float rstd = rsqrtf(var + 1e-5f);
  const float4 gv = ((const float4*)G)[t];
  const float4 bv = ((const float4*)Bt)[t];
  __hip_bfloat16* o = O + row * 1024 + t * 4;
  o[0] = __float2bfloat16((xv.x - mean) * rstd * gv.x + bv.x);
  o[1] = __float2bfloat16((xv.y - mean) * rstd * gv.y + bv.y);
  o[2] = __float2bfloat16((xv.z - mean) * rstd * gv.z + bv.z);
  o[3] = __float2bfloat16((xv.w - mean) * rstd * gv.w + bv.w);
}

// ---------------------------------------------------------------------------
// prep_weights: z 0..14 = one 1024x1024 transpose-convert each; z 15 = bias6
// concat; z 16..19 = LN1 over rows [(z-16)*1024, +1024). grid (32,32,20).
// ---------------------------------------------------------------------------
struct PrepJobs {
  const float* in[15];
  __hip_bfloat16* out[15];
  int inLd[15];
  int outLd[15];
  float scale[15];
  const float* bsrc[6];
  float bscale[6];
  float* bias6;
  const float* lnx;
  const float* lng;
  const float* lnb;
  __hip_bfloat16* lno;
};
__global__ __launch_bounds__(256) void prep_weights(PrepJobs p) {
  int j = blockIdx.z;
  int tid = threadIdx.x;
  if (j >= 16) {  // LN1 slice
    long row = (long)(j - 16) * 1024 + blockIdx.y * 32 + blockIdx.x;
    const float4 xv = ((const float4*)(p.lnx + row * 1024))[tid];
    float s = xv.x + xv.y + xv.z + xv.w;
    float q = xv.x * xv.x + xv.y * xv.y + xv.z * xv.z + xv.w * xv.w;
#pragma unroll
    for (int o = 32; o; o >>= 1) {
      s += __shfl_xor(s, o);
      q += __shfl_xor(q, o);
    }
    __shared__ float rs[4], rq[4];
    int wid = tid >> 6;
    if ((tid & 63) == 0) { rs[wid] = s; rq[wid] = q; }
    __syncthreads();
    s = rs[0] + rs[1] + rs[2] + rs[3];
    q = rq[0] + rq[1] + rq[2] + rq[3];
    float mean = s * (1.f / 1024.f);
    float var = q * (1.f / 1024.f) - mean * mean;
    float rstd = rsqrtf(var + 1e-5f);
    const float4 gv = ((const float4*)p.lng)[tid];
    const float4 bv = ((const float4*)p.lnb)[tid];
    __hip_bfloat16* o = p.lno + row * 1024 + tid * 4;
    o[0] = __float2bfloat16((xv.x - mean) * rstd * gv.x + bv.x);
    o[1] = __float2bfloat16((xv.y - mean) * rstd * gv.y + bv.y);
    o[2] = __float2bfloat16((xv.z - mean) * rstd * gv.z + bv.z);
    o[3] = __float2bfloat16((xv.w - mean) * rstd * gv.w + bv.w);
    return;
  }
  if (j == 15) {
    if (blockIdx.y == 0 && blockIdx.x < 24) {
      int idx = blockIdx.x * 256 + tid;
      int jj = idx >> 10, e = idx & 1023;
      p.bias6[idx] = p.bsrc[jj][e] * p.bscale[jj];
    }
    return;
  }
  __shared__ float t[32][33];
  const float* in = p.in[j];
  __hip_bfloat16* out = p.out[j];
  const int inLd = p.inLd[j], outLd = p.outLd[j];
  const float sc = p.scale[j];
  int c0 = blockIdx.x * 32, r0 = blockIdx.y * 32;
  int lr = tid >> 3, lc = (tid & 7) * 4;
  const float4 v = *(const float4*)&in[(long)(r0 + lr) * inLd + c0 + lc];
  t[lr][lc] = v.x; t[lr][lc + 1] = v.y; t[lr][lc + 2] = v.z; t[lr][lc + 3] = v.w;
  __syncthreads();
  int oc = tid >> 3, orr = (tid & 7) * 4;
  __hip_bfloat16* o = &out[(long)(c0 + oc) * outLd + r0 + orr];
  o[0] = __float2bfloat16(t[orr][oc] * sc);
  o[1] = __float2bfloat16(t[orr + 1][oc] * sc);
  o[2] = __float2bfloat16(t[orr + 2][oc] * sc);
  o[3] = __float2bfloat16(t[orr + 3][oc] * sc);
}

// ---------------------------------------------------------------------------
// tconv_vpv: V (z 0..7) and PV (z 8..15): [512x1024]@6144 -> [1024][512].
// ---------------------------------------------------------------------------
__global__ __launch_bounds__(256) void tconv_vpv(
    const __hip_bfloat16* __restrict__ V, const __hip_bfloat16* __restrict__ PV,
    __hip_bfloat16* __restrict__ VT, __hip_bfloat16* __restrict__ PVT) {
  __shared__ __hip_bfloat16 t[32][34];
  int z = blockIdx.z;
  const __hip_bfloat16* in = (z < 8) ? V : PV;
  __hip_bfloat16* out = (z < 8) ? VT : PVT;
  int bz = z & 7;
  long ibase = (long)bz * 512 * 6144;
  long obase = (long)bz * 512 * 1024;
  int c0 = blockIdx.x * 32, r0 = blockIdx.y * 32;
  int tid = threadIdx.x;
  int lr = tid >> 3, lc = (tid & 7) * 4;
  const __hip_bfloat16* ip = &in[ibase + (long)(r0 + lr) * 6144 + c0 + lc];
  t[lr][lc] = ip[0]; t[lr][lc + 1] = ip[1]; t[lr][lc + 2] = ip[2]; t[lr][lc + 3] = ip[3];
  __syncthreads();
  int oc = tid >> 3, orr = (tid & 7) * 4;
  __hip_bfloat16* o = &out[obase + (long)(c0 + oc) * 512 + r0 + orr];
  o[0] = t[orr][oc];
  o[1] = t[orr + 1][oc];
  o[2] = t[orr + 2][oc];
  o[3] = t[orr + 3][oc];
}

// ---------------------------------------------------------------------------
// gemm256: BM=256, BN=128, BK=32, 512 thr = 8 waves (2M x 4N). 48KB LDS.
// K-loop: {barrier(A) -> issue stage(t+1) -> vmcnt(3) -> barrier(B) ->
// read+MFMA}. Chunk swizzle s(row)=(row^(row>>2))&3 both sides. 2D XCD
// chunking. Split-K via blockIdx.z (writes C + z*sC).
// ---------------------------------------------------------------------------
__global__ __launch_bounds__(512, 2) void gemm256(
    const __hip_bfloat16* __restrict__ A, const __hip_bfloat16* __restrict__ Bt,
    const float* __restrict__ bias, void* __restrict__ C, int K, int lda,
    int ldb, int ldc, int act, int obf, long sC) {
  constexpr int ABYTES = 256 * 64;  // 16KB
  constexpr int BBYTES = 128 * 64;  // 8KB
  constexpr int BUF = ABYTES + BBYTES;
  __shared__ char lds[2 * BUF];  // 48KB

  int bx, by;
  {
    int wg = blockIdx.y * gridDim.x + blockIdx.x;
    int gx = gridDim.x, gy = gridDim.y;
    if ((gx & 3) == 0 && (gy & 1) == 0) {
      int cw = gx >> 2, ch = gy >> 1;
      int xcd = wg & 7, idx = wg >> 3;
      bx = (xcd & 3) * cw + idx % cw;
      by = (xcd >> 2) * ch + idx / cw;
    } else {
      bx = blockIdx.x;
      by = blockIdx.y;
    }
  }
  const int m0 = by * 256, n0 = bx * 128;
  const int z = blockIdx.z;
  const long kbase = (long)z * K * 2;

  const int tid = threadIdx.x;
  const int lane = tid & 63, wid = tid >> 6;
  const int wm = wid >> 2, wn = wid & 3;
  const int ll = lane & 15, lh = lane >> 4;

  const char* Ag = (const char*)A;
  const char* Bg = (const char*)Bt;
  const int srow = tid >> 2;  // 0..127
  const int ssw = (srow ^ (srow >> 2)) & 3;
  const int scb = (((tid & 3) ^ ssw) << 4);  // swizzled global src chunk
  const int sld = (tid & 3) << 4;            // linear LDS chunk

  auto stage = [&](char* base, long kb) {
#pragma unroll
    for (int l = 0; l < 2; ++l) {
      int row = l * 128 + srow;
      async_copy16(base + row * 64 + sld,
                   Ag + ((long)(m0 + row) * lda) * 2 + kb + scb);
    }
    async_copy16(base + ABYTES + srow * 64 + sld,
                 Bg + ((long)(n0 + srow) * ldb) * 2 + kb + scb);
  };

  const int rsw = (ll ^ (ll >> 2)) & 3;
  const int ckk = ((lh ^ rsw) << 4);

  f32x4 acc[8][2];
#pragma unroll
  for (int m = 0; m < 8; ++m)
#pragma unroll
    for (int n = 0; n < 2; ++n) acc[m][n] = (f32x4){0.f, 0.f, 0.f, 0.f};

  const int nt = K >> 5;
  stage(lds, kbase);

  for (int t = 0; t < nt; ++t) {
    const int bt = t & 1;
    const char* Ab = lds + bt * BUF;
    const char* Bb = Ab + ABYTES;
    char* nb = lds + (bt ^ 1) * BUF;

    SB0; BARRIER; SB0;  // (A) all waves done reading buffer bt^1
    if (t + 1 < nt) {
      stage(nb, kbase + (long)(t + 1) * 64);
      asm volatile("s_waitcnt vmcnt(3)" ::: "memory");  // retire tile t only
    } else {
      asm volatile("s_waitcnt vmcnt(0)" ::: "memory");
    }
    SB0; BARRIER; SB0;  // (B) tile-t data visible

    bf16x8 bf[2];
#pragma unroll
    for (int n = 0; n < 2; ++n)
      bf[n] = *(const bf16x8*)(Bb + (wn * 32 + n * 16 + ll) * 64 + ckk);
    bf16x8 af[4];
#pragma unroll
    for (int m = 0; m < 4; ++m)
      af[m] = *(const bf16x8*)(Ab + (wm * 128 + m * 16 + ll) * 64 + ckk);
    __builtin_amdgcn_s_setprio(1);
#pragma unroll
    for (int m = 0; m < 4; ++m)
#pragma unroll
      for (int n = 0; n < 2; ++n)
        acc[m][n] = __builtin_amdgcn_mfma_f32_16x16x32_bf16(af[m], bf[n],
                                                            acc[m][n], 0, 0, 0);
    __builtin_amdgcn_s_setprio(0);
#pragma unroll
    for (int m = 0; m < 4; ++m)
      af[m] = *(const bf16x8*)(Ab + (wm * 128 + (m + 4) * 16 + ll) * 64 + ckk);
    __builtin_amdgcn_s_setprio(1);
#pragma unroll
    for (int m = 0; m < 4; ++m)
#pragma unroll
      for (int n = 0; n < 2; ++n)
        acc[m + 4][n] = __builtin_amdgcn_mfma_f32_16x16x32_bf16(
            af[m], bf[n], acc[m + 4][n], 0, 0, 0);
    __builtin_amdgcn_s_setprio(0);
  }

#pragma unroll
  for (int m = 0; m < 8; ++m) {
    int row = m0 + wm * 128 + m * 16 + lh * 4;
#pragma unroll
    for (int n = 0; n < 2; ++n) {
      int col = n0 + wn * 32 + n * 16 + ll;
      float bs = bias ? bias[col] : 0.f;
#pragma unroll
      for (int r = 0; r < 4; ++r) {
        float v = acc[m][n][r] + bs;
        if (act) v = v * 0.5f * (1.f + erff(v * 0.70710678118f));
        long cidx = (long)z * sC + (long)(row + r) * ldc + col;
        if (obf)
          ((__hip_bfloat16*)C)[cidx] = __float2bfloat16(v);
        else
          ((float*)C)[cidx] = v;
      }
    }
  }
}

// FFN2 finalize: OUT = PART0 + PART1 + b2 + X2. float4/thread, grid 4096.
__global__ __launch_bounds__(256) void ffn2_reduce(
    const float* __restrict__ P, const float* __restrict__ X2,
    const float* __restrict__ b2, float* __restrict__ OUT) {
  int i = blockIdx.x * 256 + threadIdx.x;
  const long SP = 4194304;
  float4 a = ((const float4*)P)[i];
  float4 b = ((const float4*)(P + SP))[i];
  float4 xr = ((const float4*)X2)[i];
  const float4 bb = *(const float4*)(b2 + ((i & 255) * 4));
  float4 o;
  o.x = a.x + b.x + xr.x + bb.x;
  o.y = a.y + b.y + xr.y + bb.y;
  o.z = a.z + b.z + xr.z + bb.z;
  o.w = a.w + b.w + xr.w + bb.w;
  ((float4*)OUT)[i] = o;
}

// ---------------------------------------------------------------------------
// bf16 MFMA GEMM (NT), 128x128 tile, BK=32, 4 waves. Double-buffered LDS,
// counted vmcnt(4) pipeline. XCD swizzle. Split-K via z-packing.
// pbc=1: C = E1 + 0.5*((A@Bt^T + bias) + E2[row>>9, col]).
// ---------------------------------------------------------------------------
__global__ __launch_bounds__(256) void gemm_bf16_nt(
    const __hip_bfloat16* __restrict__ A, const __hip_bfloat16* __restrict__ Bt,
    const float* __restrict__ bias, const float* __restrict__ E1,
    const float* __restrict__ E2, void* __restrict__ C, int K, int lda,
    int ldb, int ldc, long sA, long sB, long sC, long sE, float alpha, int act,
    int obf, int pbc, int ksplit, long sSplit) {
  __shared__ unsigned short AsU[2][128 * 32];
  __shared__ unsigned short BsU[2][128 * 32];
  const int tid = threadIdx.x;
  const int lane = tid & 63, wave = tid >> 6;
  const int wr = wave >> 1, wc = wave & 1;

  int nwg = gridDim.x * gridDim.y;
  int wg = blockIdx.y * gridDim.x + blockIdx.x;
  int bx = blockIdx.x, by = blockIdx.y;
  if ((nwg & 7) == 0) {
    int cpx = nwg >> 3;
    int sw = (wg & 7) * cpx + (wg >> 3);
    bx = sw % gridDim.x;
    by = sw / gridDim.x;
  }
  const int m0 = by * 128, n0 = bx * 128;
  const int bz = blockIdx.z / ksplit;
  const int sk = blockIdx.z % ksplit;
  if (sk != 0) { bias = nullptr; E1 = nullptr; E2 = nullptr; }
  const int kcol0 = sk * K;
  const char* Ab = (const char*)(A + (long)bz * sA);
  const char* Bb = (const char*)(Bt + (long)bz * sB);

  f32x4 acc[4][4];
#pragma unroll
  for (int m = 0; m < 4; ++m)
#pragma unroll
    for (int n = 0; n < 4; ++n) acc[m][n] = (f32x4){0.f, 0.f, 0.f, 0.f};

  const int srow = tid >> 2;
  const int scol = (tid & 3) * 16;
  const int wbase = (tid >> 6) * 1024;

  auto stage = [&](int buf, int k0) {
    int kk = kcol0 + k0;
#pragma unroll
    for (int i = 0; i < 2; ++i) {
      async_copy16((char*)AsU[buf] + i * 4096 + wbase,
                   Ab + ((long)(m0 + i * 64 + srow) * lda + kk) * 2 + scol);
      async_copy16((char*)BsU[buf] + i * 4096 + wbase,
                   Bb + ((long)(n0 + i * 64 + srow) * ldb + kk) * 2 + scol);
    }
  };

  const int ntk = K >> 5;
  stage(0, 0);

  for (int t = 0; t < ntk; ++t) {
    const int bt = t & 1;
    SB0; BARRIER; SB0;
    if (t + 1 < ntk) {
      stage(bt ^ 1, (t + 1) * 32);
      asm volatile("s_waitcnt vmcnt(4)" ::: "memory");
    } else {
      asm volatile("s_waitcnt vmcnt(0)" ::: "memory");
    }
    SB0; BARRIER; SB0;

    const int koff = (lane >> 4) * 8;
    bf16x8 a[4], b[4];
#pragma unroll
    for (int m = 0; m < 4; ++m)
      a[m] = *(const bf16x8*)&AsU[bt][(wr * 64 + m * 16 + (lane & 15)) * 32 +
                                      koff];
#pragma unroll
    for (int n = 0; n < 4; ++n)
      b[n] = *(const bf16x8*)&BsU[bt][(wc * 64 + n * 16 + (lane & 15)) * 32 +
                                      koff];
    __builtin_amdgcn_s_setprio(1);
#pragma unroll
    for (int m = 0; m < 4; ++m)
#pragma unroll
      for (int n = 0; n < 4; ++n)
        acc[m][n] = __builtin_amdgcn_mfma_f32_16x16x32_bf16(a[m], b[n],
                                                            acc[m][n], 0, 0, 0);
    __builtin_amdgcn_s_setprio(0);
  }

#pragma unroll
  for (int m = 0; m < 4; ++m) {
    int row = m0 + wr * 64 + m * 16 + (lane >> 4) * 4;
#pragma unroll
    for (int n = 0; n < 4; ++n) {
      int col = n0 + wc * 64 + n * 16 + (lane & 15);
      float bs = bias ? bias[col] : 0.f;
#pragma unroll
      for (int r = 0; r < 4; ++r) {
        float v = (acc[m][n][r] + bs) * alpha;
        if (pbc) {
          v = E1[(long)(row + r) * ldc + col] +
              0.5f * (v + E2[(long)((row + r) >> 9) * 1024 + col]);
        } else {
          long eidx = (long)bz * sE + (long)(row + r) * ldc + col;
          if (E1) v += E1[eidx];
          if (E2) v += E2[eidx];
        }
        if (act) v = v * 0.5f * (1.f + erff(v * 0.70710678118f));
        long cidx = (long)bz * sC + (long)sk * sSplit +
                    (long)(row + r) * ldc + col;
        if (obf)
          ((__hip_bfloat16*)C)[cidx] = __float2bfloat16(v);
        else
          ((float*)C)[cidx] = v;
      }
    }
  }
}

// ---------------------------------------------------------------------------
// MFMA attention. Block = (i-tile of 32, h, b); 4 waves. Reads bias+mask raw.
// ---------------------------------------------------------------------------
__global__ __launch_bounds__(256) void attn_mfma(
    const __hip_bfloat16* __restrict__ Q, const __hip_bfloat16* __restrict__ K,
    const __hip_bfloat16* __restrict__ VT, const float* __restrict__ BiasP,
    const float* __restrict__ MaskP, __hip_bfloat16* __restrict__ O,
    int ldqk) {
  __shared__ __hip_bfloat16 P[32][520];
  __shared__ float red[2][32][4];
  const int it = blockIdx.x, h = blockIdx.y, b = blockIdx.z;
  const int i0 = it * 32;
  const int tid = threadIdx.x;
  const int lane = tid & 63, w = tid >> 6;
  const int lh = lane >> 4, ll = lane & 15;

  const long qkb = (long)b * 512 * ldqk + h * 64;

  bf16x8 a[2][2];
#pragma unroll
  for (int m = 0; m < 2; ++m)
#pragma unroll
    for (int ks = 0; ks < 2; ++ks)
      a[m][ks] = *(const bf16x8*)&Q[qkb + (long)(i0 + m * 16 + ll) * ldqk +
                                    ks * 32 + lh * 8];

  f32x4 acc[2][8];
#pragma unroll
  for (int m = 0; m < 2; ++m)
#pragma unroll
    for (int n = 0; n < 8; ++n) acc[m][n] = (f32x4){0.f, 0.f, 0.f, 0.f};

#pragma unroll
  for (int n = 0; n < 8; ++n) {
    const __hip_bfloat16* kp =
        &K[qkb + (long)(w * 128 + n * 16 + ll) * ldqk + lh * 8];
    bf16x8 b0 = *(const bf16x8*)&kp[0];
    bf16x8 b1 = *(const bf16x8*)&kp[32];
#pragma unroll
    for (int m = 0; m < 2; ++m) {
      acc[m][n] =
          __builtin_amdgcn_mfma_f32_16x16x32_bf16(a[m][0], b0, acc[m][n], 0, 0, 0);
      acc[m][n] =
          __builtin_amdgcn_mfma_f32_16x16x32_bf16(a[m][1], b1, acc[m][n], 0, 0, 0);
    }
  }

  const long bmo = ((long)b * 512 + i0) * 512 + w * 128;
#pragma unroll
  for (int m = 0; m < 2; ++m)
#pragma unroll
    for (int r = 0; r < 4; ++r) {
      int row = m * 16 + lh * 4 + r;
#pragma unroll
      for (int n = 0; n < 8; ++n) {
        long gi = bmo + (long)row * 512 + n * 16 + ll;
        acc[m][n][r] += BiasP[gi] + MaskP[gi];
      }
    }

  float rmax[2][4];
#pragma unroll
  for (int m = 0; m < 2; ++m)
#pragma unroll
    for (int r = 0; r < 4; ++r) {
      float v = acc[m][0][r];
#pragma unroll
      for (int n = 1; n < 8; ++n) v = fmaxf(v, acc[m][n][r]);
#pragma unroll
      for (int o = 1; o < 16; o <<= 1) v = fmaxf(v, __shfl_xor(v, o));
      rmax[m][r] = v;
    }
  if (ll == 0) {
#pragma unroll
    for (int m = 0; m < 2; ++m)
#pragma unroll
      for (int r = 0; r < 4; ++r) red[0][m * 16 + lh * 4 + r][w] = rmax[m][r];
  }
  __syncthreads();
#pragma unroll
  for (int m = 0; m < 2; ++m)
#pragma unroll
    for (int r = 0; r < 4; ++r) {
      const float* p = red[0][m * 16 + lh * 4 + r];
      rmax[m][r] = fmaxf(fmaxf(p[0], p[1]), fmaxf(p[2], p[3]));
    }
  float rsum[2][4];
#pragma unroll
  for (int m = 0; m < 2; ++m)
#pragma unroll
    for (int r = 0; r < 4; ++r) {
      float s = 0.f;
#pragma unroll
      for (int n = 0; n < 8; ++n) {
        float e = __expf(acc[m][n][r] - rmax[m][r]);
        acc[m][n][r] = e;
        s += e;
      }
#pragma unroll
      for (int o = 1; o < 16; o <<= 1) s += __shfl_xor(s, o);
      rsum[m][r] = s;
    }
  if (ll == 0) {
#pragma unroll
    for (int m = 0; m < 2; ++m)
#pragma unroll
      for (int r = 0; r < 4; ++r) red[1][m * 16 + lh * 4 + r][w] = rsum[m][r];
  }
  __syncthreads();
#pragma unroll
  for (int m = 0; m < 2; ++m)
#pragma unroll
    for (int r = 0; r < 4; ++r) {
      const float* p = red[1][m * 16 + lh * 4 + r];
      float inv = 1.f / (p[0] + p[1] + p[2] + p[3]);
      int row = m * 16 + lh * 4 + r;
#pragma unroll
      for (int n = 0; n < 8; ++n)
        P[row][w * 128 + n * 16 + ll] = __float2bfloat16(acc[m][n][r] * inv);
    }
  __syncthreads();

  const long vtb = ((long)b * 1024 + h * 64) * 512;
  const long ob = (long)b * 512 * 1024 + h * 64;
  const int mw = (w >> 1) * 16, nw = (w & 1) * 32;
  f32x4 oacc[2];
  oacc[0] = (f32x4){0.f, 0.f, 0.f, 0.f};
  oacc[1] = (f32x4){0.f, 0.f, 0.f, 0.f};
#pragma unroll
  for (int ks = 0; ks < 16; ++ks) {
    int k0 = ks * 32;
    bf16x8 pa = *(const bf16x8*)&P[mw + ll][k0 + lh * 8];
#pragma unroll
    for (int nf = 0; nf < 2; ++nf) {
      bf16x8 vb = *(const bf16x8*)&VT[vtb + (long)(nw + nf * 16 + ll) * 512 +
                                      k0 + lh * 8];
      oacc[nf] =
          __builtin_amdgcn_mfma_f32_16x16x32_bf16(pa, vb, oacc[nf], 0, 0, 0);
    }
  }
#pragma unroll
  for (int nf = 0; nf < 2; ++nf)
#pragma unroll
    for (int r = 0; r < 4; ++r)
      O[ob + (long)(i0 + mw + lh * 4 + r) * 1024 + nw + nf * 16 + ll] =
          __float2bfloat16(oacc[nf][r]);
}

// ---------------------------------------------------------------------------
// Row softmax over 512 of (P0[row] + P1[row]) -> bf16. One block per row.
// ---------------------------------------------------------------------------
__global__ __launch_bounds__(256) void softmax_rows2(
    const float* __restrict__ P0, const float* __restrict__ P1,
    __hip_bfloat16* __restrict__ Ob) {
  const float* r0 = P0 + (long)blockIdx.x * 512;
  const float* r1 = P1 + (long)blockIdx.x * 512;
  __hip_bfloat16* orow = Ob + (long)blockIdx.x * 512;
  int t = threadIdx.x;
  float v0 = r0[t] + r1[t], v1 = r0[t + 256] + r1[t + 256];
  float m = fmaxf(v0, v1);
#pragma unroll
  for (int o = 32; o; o >>= 1) m = fmaxf(m, __shfl_xor(m, o));
  __shared__ float red[8];
  int wid = t >> 6, lane = t & 63;
  if (!lane) red[wid] = m;
  __syncthreads();
  m = fmaxf(fmaxf(red[0], red[1]), fmaxf(red[2], red[3]));
  float e0 = __expf(v0 - m), e1 = __expf(v1 - m);
  float s = e0 + e1;
#pragma unroll
  for (int o = 32; o; o >>= 1) s += __shfl_xor(s, o);
  if (!lane) red[4 + wid] = s;
  __syncthreads();
  s = red[4] + red[5] + red[6] + red[7];
  float inv = 1.f / s;
  orow[t] = __float2bfloat16(e0 * inv);
  orow[t + 256] = __float2bfloat16(e1 * inv);
}

// ---------------------------------------------------------------------------
// path gather-mean partials + finalize.
// ---------------------------------------------------------------------------
__global__ __launch_bounds__(256) void path_partial(
    const float* __restrict__ xp, const int* __restrict__ pp,
    float* __restrict__ PP, float* __restrict__ WS) {
  int b = blockIdx.x, hc = blockIdx.y, ic = blockIdx.z;
  int h = hc * 256 + threadIdx.x;
  const int* ppb = pp + b * 512;
  const float* xb = xp + (long)b * 512 * 1024;
  int iA = ic * 64, iB = iA + 64;
  float acc = 0.f;
  for (int i = iA; i < iB; ++i) {
    if (ppb[i] != 1) continue;
    float cur = xb[(long)i * 1024 + h];
    float a;
    if (i == 0) {
      a = 0.5f * (cur + xb[1024 + h]);
    } else if (i == 1) {
      a = (xb[h] + cur + xb[2 * 1024 + h]) * (1.f / 3.f);
    } else {
      int inx = (i + 1 < 512) ? i + 1 : 511;
      float nx = xb[(long)inx * 1024 + h];
      if (ppb[i - 2] == 1) {
        a = 0.5f * (cur + nx);
      } else {
        a = (xb[(long)(i - 1) * 1024 + h] + cur + nx) * (1.f / 3.f);
      }
    }
    acc += a;
  }
  PP[((long)b * 8 + ic) * 1024 + h] = acc;
  if (hc == 0 && threadIdx.x == 0) {
    float c = 0.f;
    for (int i = iA; i < iB; ++i) c += (ppb[i] == 1) ? 1.f : 0.f;
    WS[b * 8 + ic] = c;
  }
}

__global__ __launch_bounds__(256) void path_finalize(
    const float* __restrict__ PP, const float* __restrict__ WS,
    float* __restrict__ PATH) {
  int b = blockIdx.x;
  int h = blockIdx.y * 256 + threadIdx.x;
  float s = 0.f, w = 0.f;
#pragma unroll
  for (int ic = 0; ic < 8; ++ic) {
    s += PP[((long)b * 8 + ic) * 1024 + h];
    w += WS[b * 8 + ic];
  }
  PATH[b * 1024 + h] = s / w;
}

// ---------------------------------------------------------------------------
extern "C" void kernel_launch(void* const* d_in, const int* in_sizes, int n_in,
                              void* d_out, int out_size, void* d_ws,
                              size_t ws_size, hipStream_t stream) {
  const float* x = (const float*)d_in[0];
  const int* pp = (const int*)d_in[1];
  const float* abias = (const float*)d_in[3];
  const float* amask = (const float*)d_in[4];
  const float* agraph = (const float*)d_in[5];
  const float* vgraph = (const float*)d_in[6];
  const float* ln1g = (const float*)d_in[7];
  const float* ln1b = (const float*)d_in[8];
  const float* wq = (const float*)d_in[9];
  const float* bq = (const float*)d_in[10];
  const float* wk = (const float*)d_in[11];
  const float* bk = (const float*)d_in[12];
  const float* wv = (const float*)d_in[13];
  const float* bv = (const float*)d_in[14];
  const float* wo = (const float*)d_in[15];
  const float* bo = (const float*)d_in[16];
  const float* pqw = (const float*)d_in[17];
  const float* pqb = (const float*)d_in[18];
  const float* pkw = (const float*)d_in[19];
  const float* pkb = (const float*)d_in[20];
  const float* pvw = (const float*)d_in[21];
  const float* pvb = (const float*)d_in[22];
  const float* ln2g = (const float*)d_in[23];
  const float* ln2b = (const float*)d_in[24];
  const float* w1 = (const float*)d_in[25];
  const float* b1 = (const float*)d_in[26];
  const float* w2 = (const float*)d_in[27];
  const float* b2 = (const float*)d_in[28];

  char* wsb = (char*)d_ws;
  auto Ybf = (__hip_bfloat16*)(wsb);                  // 0-8 (later Y2b)
  auto QKV = (__hip_bfloat16*)(wsb + (8l << 20));     // 8-56: [4096][6144]
  auto VTb = (__hip_bfloat16*)(wsb + (56l << 20));    // 56-64
  auto PVT = (__hip_bfloat16*)(wsb + (64l << 20));    // 64-72
  auto ATTb = (__hip_bfloat16*)(wsb + (72l << 20));   // 72-80
  auto PATTb = (__hip_bfloat16*)(wsb + (88l << 20));  // 88-92
  auto PATTf = (float*)(wsb + (92l << 20));           // 92-100 (partial0)
  auto XP = (float*)(wsb + (92l << 20));              // 92-108
  auto WALL = (__hip_bfloat16*)(wsb + (108l << 20));  // 108-120: [6144][1024]
  auto WOT = (__hip_bfloat16*)(wsb + (120l << 20));   // 120-122
  auto W1T = (__hip_bfloat16*)(wsb + (122l << 20));   // 122-130
  auto bias6 = (float*)(wsb + (130l << 20));          // 24KB
  auto PPart = (float*)(wsb + (131l << 20));          // 256KB
  auto WSp = (float*)(wsb + (132l << 20));            // 256B
  auto PATH = (float*)(wsb + (133l << 20));           // 32KB
  auto X2 = (float*)(wsb + (24l << 20));              // 24-40 (QKV dead)
  auto HMID = (__hip_bfloat16*)(wsb + (40l << 20));   // 40-72
  auto PART = (float*)(wsb + (92l << 20));            // 92-124 (2x16MB f32)
  auto W2T = (__hip_bfloat16*)(wsb + (156l << 20));   // 156-164
  __hip_bfloat16* Y2b = Ybf;
  float* OUT = (float*)d_out;

  const float qscale = 0.125f;
  const float pscale = 0.03125f;
  const long S2 = 512l * 512;
  const long SQ = 512l * 6144;
  const long SPLT = 8l * S2;

  __hip_bfloat16* Qp = QKV;
  __hip_bfloat16* Kp = QKV + 1024;
  __hip_bfloat16* Vp = QKV + 2048;
  __hip_bfloat16* PQp = QKV + 3072;
  __hip_bfloat16* PKp = QKV + 4096;
  __hip_bfloat16* PVp = QKV + 5120;

  // 0) ALL weight prep + bias concat + LN1 in ONE launch (z = 20 slices)
  PrepJobs pj;
  pj.in[0] = wq;  pj.out[0] = WALL;               pj.inLd[0] = 1024; pj.outLd[0] = 1024; pj.scale[0] = qscale;
  pj.in[1] = wk;  pj.out[1] = WALL + 1024 * 1024; pj.inLd[1] = 1024; pj.outLd[1] = 1024; pj.scale[1] = 1.f;
  pj.in[2] = wv;  pj.out[2] = WALL + 2048 * 1024; pj.inLd[2] = 1024; pj.outLd[2] = 1024; pj.scale[2] = 1.f;
  pj.in[3] = pqw; pj.out[3] = WALL + 3072 * 1024; pj.inLd[3] = 1024; pj.outLd[3] = 1024; pj.scale[3] = pscale;
  pj.in[4] = pkw; pj.out[4] = WALL + 4096 * 1024; pj.inLd[4] = 1024; pj.outLd[4] = 1024; pj.scale[4] = 1.f;
  pj.in[5] = pvw; pj.out[5] = WALL + 5120 * 1024; pj.inLd[5] = 1024; pj.outLd[5] = 1024; pj.scale[5] = 1.f;
  pj.in[6] = wo;  pj.out[6] = WOT;                pj.inLd[6] = 1024; pj.outLd[6] = 1024; pj.scale[6] = 1.f;
  for (int j = 0; j < 4; ++j) {  // w1: [1024,4096] -> W1T [4096][1024]
    pj.in[7 + j] = w1 + j * 1024;
    pj.out[7 + j] = W1T + (long)j * 1024 * 1024;
    pj.inLd[7 + j] = 4096;
    pj.outLd[7 + j] = 1024;
    pj.scale[7 + j] = 1.f;
  }
  for (int j = 0; j < 4; ++j) {  // w2: [4096,1024] -> W2T [1024][4096]
    pj.in[11 + j] = w2 + (long)j * 1024 * 1024;
    pj.out[11 + j] = W2T + j * 1024;
    pj.inLd[11 + j] = 1024;
    pj.outLd[11 + j] = 4096;
    pj.scale[11 + j] = 1.f;
  }
  pj.bsrc[0] = bq;  pj.bscale[0] = qscale;
  pj.bsrc[1] = bk;  pj.bscale[1] = 1.f;
  pj.bsrc[2] = bv;  pj.bscale[2] = 1.f;
  pj.bsrc[3] = pqb; pj.bscale[3] = pscale;
  pj.bsrc[4] = pkb; pj.bscale[4] = 1.f;
  pj.bsrc[5] = pvb; pj.bscale[5] = 1.f;
  pj.bias6 = bias6;
  pj.lnx = x; pj.lng = ln1g; pj.lnb = ln1b; pj.lno = Ybf;
  prep_weights<<<dim3(32, 32, 20), 256, 0, stream>>>(pj);

  // 2) fused projections: M=4096 (y=16), N=6144 (x=48)
  gemm256<<<dim3(48, 16, 1), 512, 0, stream>>>(
      Ybf, WALL, bias6, QKV, 1024, 1024, 1024, 6144, 0, 1, 0);

  // 3) V -> VT and PV -> PVT in one launch
  tconv_vpv<<<dim3(32, 16, 16), 256, 0, stream>>>(Vp, PVp, VTb, PVT);

  // 4) path scores split-K=2 + softmax over partials
  gemm_bf16_nt<<<dim3(4, 4, 16), 256, 0, stream>>>(
      PQp, PKp, nullptr, agraph, vgraph, PATTf, 512, 6144, 6144, 512, SQ, SQ,
      S2, S2, 1.f, 0, 0, 0, 2, SPLT);
  softmax_rows2<<<4096, 256, 0, stream>>>(PATTf, PATTf + SPLT, PATTb);

  // 5) MFMA attention -> ATTb
  attn_mfma<<<dim3(16, 16, 8), 256, 0, stream>>>(Qp, Kp, VTb, abias, amask,
                                                 ATTb, 6144);

  // 6) XP = PATT @ PVT^T
  gemm_bf16_nt<<<dim3(8, 4, 8), 256, 0, stream>>>(
      PATTb, PVT, nullptr, nullptr, nullptr, XP, 512, 512, 512, 1024, S2,
      512l * 1024, 512l * 1024, 0, 1.f, 0, 0, 0, 1, 0);

  // 7) path gather-mean
  path_partial<<<dim3(8, 4, 8), 256, 0, stream>>>(XP, pp, PPart, WSp);
  path_finalize<<<dim3(8, 4), 256, 0, stream>>>(PPart, WSp, PATH);

  // 8) fused: X2 = x + 0.5*((ATT@wo + bo) + PATH)
  gemm_bf16_nt<<<dim3(8, 32, 1), 256, 0, stream>>>(
      ATTb, WOT, bo, x, PATH, X2, 1024, 1024, 1024, 1024, 0, 0, 0, 0, 1.f, 0,
      0, 1, 1, 0);

  // 10) LN2 -> Y2b
  ln_rows_bf16<<<4096, 256, 0, stream>>>(X2, ln2g, ln2b, Y2b);

  // 11) FFN1: M=4096 (y=16), N=4096 (x=32), GELU, bf16 out
  gemm256<<<dim3(32, 16, 1), 512, 0, stream>>>(
      Y2b, W1T, b1, HMID, 1024, 1024, 1024, 4096, 1, 1, 0);

  // 12) FFN2 split-K=2: grid (8,16,2) = 256 blocks, K=2048 per split
  gemm256<<<dim3(8, 16, 2), 512, 0, stream>>>(
      HMID, W2T, nullptr, PART, 2048, 4096, 4096, 1024, 0, 0, 4194304);

  // 12b) OUT = PART0 + PART1 + b2 + X2
  ffn2_reduce<<<4096, 256, 0, stream>>>(PART, X2, b2, OUT);
}